// Round 1
// baseline (1476.025 us; speedup 1.0000x reference)
//
#include <hip/hip_runtime.h>
#include <math.h>

// IDMPNN fused forward, fp32 baseline.
// B=64 graphs, NM=32 nodes, NS=32 subgraphs/graph, K=3, HID=64, NLAYER=4, P=K!=6.
// One block per subgraph (2048 blocks). All per-perm work is independent until the
// perm-mean, so we loop p with a small 32x64 h tile in LDS (double-buffered).
// Wave-per-8-rows, lane=d; cross-lane dots via v_readlane (VALU, not LDS pipe).

#define NBATCH 64
#define NM 32
#define NS 32
#define KSUB 3
#define HID 64
#define NLAYER 4
#define PP 6
#define STOT (NBATCH * NS)

// itertools.permutations(range(3)) transposed: allperm[i][p] = perm_p[i]
__constant__ int c_perm[KSUB][PP] = {
    {0, 0, 1, 1, 2, 2},
    {1, 2, 0, 2, 0, 1},
    {2, 1, 2, 0, 1, 0}
};

__device__ __forceinline__ float rlane(float v, int l) {
    return __uint_as_float((unsigned)__builtin_amdgcn_readlane((int)__float_as_uint(v), l));
}

extern "C" __global__ void __launch_bounds__(256, 4)
idmpnn_main(const int* __restrict__ xg, const float* __restrict__ subadj,
            const int* __restrict__ subgs, const int* __restrict__ num_node,
            const float* __restrict__ idemb, const float* __restrict__ node_emb,
            const float* __restrict__ w1g, const float* __restrict__ b1g,
            const float* __restrict__ w2g, const float* __restrict__ b2g,
            const float* __restrict__ lng, const float* __restrict__ lnb,
            const float* __restrict__ s1w, const float* __restrict__ s1b,
            const float* __restrict__ s2w, const float* __restrict__ s2b,
            float* __restrict__ ws)
{
    __shared__ float aS[NM * NM];        // 4 KB  adjacency for this subgraph's graph
    __shared__ float hP[NM * HID];       // 8 KB  h (current)
    __shared__ float hN[NM * HID];       // 8 KB  h (next)
    __shared__ float hmS[NM * HID];      // 8 KB  sum over perms -> mean
    __shared__ float partS[4 * HID];     // 1 KB  per-wave partials for node-sum

    const int s    = blockIdx.x;
    const int b    = s >> 5;             // graph id (NS=32)
    const int tid  = threadIdx.x;
    const int w    = tid >> 6;           // wave id 0..3
    const int lane = tid & 63;           // d

    // Stage adjacency: 1024 floats, one float4 per thread.
    {
        const float4* src = (const float4*)(subadj + (size_t)b * NM * NM);
        ((float4*)aS)[tid] = src[tid];
    }

    // Preload node embeddings for my 8 rows (same across perms).
    float ev[8];
#pragma unroll
    for (int r = 0; r < 8; ++r) {
        int i  = w * 8 + r;
        int zi = xg[b * NM + i];
        ev[r]  = node_emb[zi * HID + lane];
    }
    __syncthreads();

    // Preload my adjacency rows: arow[r] holds A[i][lane&31] in lanes 0..31.
    float arow[8];
#pragma unroll
    for (int r = 0; r < 8; ++r) arow[r] = aS[(w * 8 + r) * NM + (lane & 31)];

    const int nd0 = subgs[s * KSUB + 0];
    const int nd1 = subgs[s * KSUB + 1];
    const int nd2 = subgs[s * KSUB + 2];

    for (int p = 0; p < PP; ++p) {
        // ---- init h for this perm ----
#pragma unroll
        for (int r = 0; r < 8; ++r) hP[(w * 8 + r) * HID + lane] = ev[r];
        __syncthreads();
        if (w < KSUB) {
            int node = (w == 0) ? nd0 : ((w == 1) ? nd1 : nd2);
            hP[node * HID + lane] *= idemb[c_perm[w][p] * HID + lane];
        }
        __syncthreads();

        float* hc = hP;
        float* hn = hN;
        for (int l = 0; l < NLAYER; ++l) {
            const float* W1 = w1g + l * HID * HID;
            const float* W2 = w2g + l * HID * HID;
            const float bv1 = b1g[l * HID + lane];
            const float bv2 = b2g[l * HID + lane];
            const float gv  = lng[l * HID + lane];
            const float bev = lnb[l * HID + lane];

            // ---- einsum: m[i][lane] = sum_j A[i][j] * h[j][lane] ----
            float m[8];
#pragma unroll
            for (int r = 0; r < 8; ++r) m[r] = 0.f;
#pragma unroll
            for (int j = 0; j < NM; ++j) {
                float hv = hc[j * HID + lane];
#pragma unroll
                for (int r = 0; r < 8; ++r) m[r] += rlane(arow[r], j) * hv;
            }

            // ---- t = relu(m @ W1 + b1) ----
            float t[8];
#pragma unroll
            for (int r = 0; r < 8; ++r) t[r] = 0.f;
#pragma unroll
            for (int e = 0; e < HID; ++e) {
                float wv = W1[e * HID + lane];
#pragma unroll
                for (int r = 0; r < 8; ++r) t[r] += rlane(m[r], e) * wv;
            }
#pragma unroll
            for (int r = 0; r < 8; ++r) t[r] = fmaxf(t[r] + bv1, 0.f);

            // ---- u = t @ W2 + b2 ----
            float u[8];
#pragma unroll
            for (int r = 0; r < 8; ++r) u[r] = 0.f;
#pragma unroll
            for (int e = 0; e < HID; ++e) {
                float wv = W2[e * HID + lane];
#pragma unroll
                for (int r = 0; r < 8; ++r) u[r] += rlane(t[r], e) * wv;
            }

            // ---- layernorm over d, relu, residual ----
#pragma unroll
            for (int r = 0; r < 8; ++r) {
                float v  = u[r] + bv2;
                float s1 = v, s2 = v * v;
#pragma unroll
                for (int off = 32; off > 0; off >>= 1) {
                    s1 += __shfl_xor(s1, off, 64);
                    s2 += __shfl_xor(s2, off, 64);
                }
                float mean = s1 * (1.0f / HID);
                float var  = s2 * (1.0f / HID) - mean * mean;
                float y    = (v - mean) * rsqrtf(var + 1e-5f) * gv + bev;
                y          = fmaxf(y, 0.f);
                int idx    = (w * 8 + r) * HID + lane;
                hn[idx]    = hc[idx] + y;
            }
            __syncthreads();
            float* tmp = hc; hc = hn; hn = tmp;
        }
        // 4 swaps -> hc == hP again. Accumulate perm sum (own rows only, no race).
#pragma unroll
        for (int r = 0; r < 8; ++r) {
            int idx = (w * 8 + r) * HID + lane;
            float v = hc[idx];
            if (p == 0) hmS[idx] = v; else hmS[idx] += v;
        }
    }

    // ---- null-mask padded nodes, perm mean ----
    const int nn = num_node[b];
#pragma unroll
    for (int r = 0; r < 8; ++r) {
        int i   = w * 8 + r;
        int idx = i * HID + lane;
        float v = hmS[idx] * (1.0f / PP);
        hmS[idx] = (i < nn) ? v : 0.f;
    }
    __syncthreads();

    // ---- h1 = relu(hm @ set1_W + set1_b); partial node-sum per wave ----
    float hr[8];
#pragma unroll
    for (int r = 0; r < 8; ++r) hr[r] = hmS[(w * 8 + r) * HID + lane];
    float h1[8];
#pragma unroll
    for (int r = 0; r < 8; ++r) h1[r] = 0.f;
#pragma unroll
    for (int e = 0; e < HID; ++e) {
        float wv = s1w[e * HID + lane];
#pragma unroll
        for (int r = 0; r < 8; ++r) h1[r] += rlane(hr[r], e) * wv;
    }
    const float sb1 = s1b[lane];
    float ps = 0.f;
#pragma unroll
    for (int r = 0; r < 8; ++r) ps += fmaxf(h1[r] + sb1, 0.f);
    partS[w * HID + lane] = ps;
    __syncthreads();

    // ---- node sum (includes padded rows' relu(set1_b), matching reference) ----
    float hsum = partS[lane] + partS[HID + lane] + partS[2 * HID + lane] + partS[3 * HID + lane];

    // ---- h2 = relu(hsum @ set2_W + set2_b), write per-subgraph vector ----
    float acc = 0.f;
#pragma unroll
    for (int e = 0; e < HID; ++e) acc += rlane(hsum, e) * s2w[e * HID + lane];
    float h2 = fmaxf(acc + s2b[lane], 0.f);
    if (tid < HID) ws[(size_t)s * HID + tid] = h2;
}

// segment_max over NS subgraphs per graph, then @ out_W + out_b
extern "C" __global__ void idmpnn_final(const float* __restrict__ ws,
                                        const float* __restrict__ outw,
                                        const float* __restrict__ outb,
                                        float* __restrict__ out)
{
    int b    = blockIdx.x;
    int lane = threadIdx.x;
    float mx = -INFINITY;
    for (int t = 0; t < NS; ++t)
        mx = fmaxf(mx, ws[((size_t)b * NS + t) * HID + lane]);
    float v = mx * outw[lane];   // OUT=1: out_W[(d,0)]
#pragma unroll
    for (int off = 32; off > 0; off >>= 1) v += __shfl_xor(v, off, 64);
    if (lane == 0) out[b] = v + outb[0];
}

extern "C" void kernel_launch(void* const* d_in, const int* in_sizes, int n_in,
                              void* d_out, int out_size, void* d_ws, size_t ws_size,
                              hipStream_t stream)
{
    const int*   xg       = (const int*)d_in[0];
    const float* subadj   = (const float*)d_in[1];
    const int*   subgs    = (const int*)d_in[2];
    const int*   num_node = (const int*)d_in[3];
    // d_in[4] num_subg unused (constant NS)
    const float* idemb    = (const float*)d_in[5];
    const float* node_emb = (const float*)d_in[6];
    const float* w1       = (const float*)d_in[7];
    const float* b1       = (const float*)d_in[8];
    const float* w2       = (const float*)d_in[9];
    const float* b2       = (const float*)d_in[10];
    const float* g        = (const float*)d_in[11];
    const float* be       = (const float*)d_in[12];
    const float* s1w      = (const float*)d_in[13];
    const float* s1b      = (const float*)d_in[14];
    const float* s2w      = (const float*)d_in[15];
    const float* s2b      = (const float*)d_in[16];
    const float* outw     = (const float*)d_in[17];
    const float* outb     = (const float*)d_in[18];
    float* wsf = (float*)d_ws;

    idmpnn_main<<<STOT, 256, 0, stream>>>(xg, subadj, subgs, num_node, idemb, node_emb,
                                          w1, b1, w2, b2, g, be,
                                          s1w, s1b, s2w, s2b, wsf);
    idmpnn_final<<<NBATCH, 64, 0, stream>>>(wsf, outw, outb, (float*)d_out);
}

// Round 2
// 444.845 us; speedup vs baseline: 3.3181x; 3.3181x over previous
//
#include <hip/hip_runtime.h>
#include <math.h>

// IDMPNN fused forward — bf16 hi/lo split MFMA version.
// B=64, NM=32, NS=32, K=3, HID=64, NLAYER=4, P=6. One block per subgraph.
// Reorder (A@h)@W1 = A@(h@W1) so every GEMM contracts the previous output's
// row dim -> C-layout writes land contiguously for the next operand read.
// h residual + LayerNorm kept in fp32 VGPRs (C-layout). Weights pre-split
// into bf16 hi/lo transposed planes in d_ws by a prep kernel.

#define NBATCH 64
#define NM 32
#define NS 32
#define KSUB 3
#define HID 64
#define NLAYER 4
#define PP 6
#define STOT (NBATCH * NS)

// d_ws layout (ushort element offsets for weight planes)
#define W1H 0
#define W1L 16384
#define W2H 32768
#define W2L 49152
#define S1H 65536
#define S1L 69632
#define H2_BYTE_OFF 163840   // float[STOT*HID] after the planes

typedef short bf16x8 __attribute__((ext_vector_type(8)));
typedef float f32x4 __attribute__((ext_vector_type(4)));

#define MFMA(a, b, c) __builtin_amdgcn_mfma_f32_16x16x32_bf16(a, b, c, 0, 0, 0)

// itertools.permutations(range(3)) transposed: c_perm[pos][p]
__constant__ int c_perm[KSUB][PP] = {
    {0, 0, 1, 1, 2, 2},
    {1, 2, 0, 2, 0, 1},
    {2, 1, 2, 0, 1, 0}
};

__device__ __forceinline__ unsigned short bf_hi(float x) {
    unsigned u = __float_as_uint(x);
    return (unsigned short)((u + 0x7FFFu + ((u >> 16) & 1u)) >> 16);  // RNE
}
__device__ __forceinline__ float bf_f(unsigned short h) {
    return __uint_as_float(((unsigned)h) << 16);
}

// ---- prep: split W1^T / W2^T / set1_W^T into bf16 hi/lo planes in ws ----
// plane layout: [l][d_out][e] (e contiguous) so B-fragments read 16B runs.
extern "C" __global__ void idmpnn_prep(const float* __restrict__ w1,
                                       const float* __restrict__ w2,
                                       const float* __restrict__ s1w,
                                       unsigned short* __restrict__ wsu)
{
    int idx = blockIdx.x * 256 + threadIdx.x;
    float v; int dh, dl;
    if (idx < 16384) {                       // W1: [l][dp][e] <- w1[l][e][dp]
        int l = idx >> 12, r = idx & 4095, dp = r >> 6, e = r & 63;
        v = w1[l * 4096 + e * 64 + dp];
        dh = W1H + idx; dl = W1L + idx;
    } else if (idx < 32768) {                // W2
        int k = idx - 16384;
        int l = k >> 12, r = k & 4095, dp = r >> 6, e = r & 63;
        v = w2[l * 4096 + e * 64 + dp];
        dh = W2H + k; dl = W2L + k;
    } else if (idx < 36864) {                // set1_W
        int k = idx - 32768, dp = k >> 6, e = k & 63;
        v = s1w[e * 64 + dp];
        dh = S1H + k; dl = S1L + k;
    } else return;
    unsigned short hi = bf_hi(v);
    wsu[dh] = hi;
    wsu[dl] = bf_hi(v - bf_f(hi));
}

extern "C" __global__ void __launch_bounds__(256, 2)
idmpnn_main(const int* __restrict__ xg, const float* __restrict__ subadj,
            const int* __restrict__ subgs, const int* __restrict__ num_node,
            const float* __restrict__ idemb, const float* __restrict__ node_emb,
            const float* __restrict__ b1g, const float* __restrict__ b2g,
            const float* __restrict__ lngm, const float* __restrict__ lnbm,
            const float* __restrict__ s1bm, const float* __restrict__ s2wm,
            const float* __restrict__ s2bm,
            const unsigned short* __restrict__ wsu, float* __restrict__ h2out)
{
    // LDS. Strides padded for alignment (16B rows) + conflict spread.
    __shared__ unsigned short AH[NM * 40], AL[NM * 40];     // adj planes [i][j]
    __shared__ unsigned short XH[NM * 72], XL[NM * 72];     // [row][d] (h/t/hm)
    __shared__ unsigned short YH[HID * 40], YL[HID * 40];   // [d'][row] (g^T)
    __shared__ float P1[NM * 4], P2[NM * 4];                // LN partials
    __shared__ float HS[HID];                               // column sums

    const int s = blockIdx.x, b = s >> 5;
    const int tid = threadIdx.x;
    const int w = tid >> 6, lane = tid & 63;
    const int c = lane & 15, gq = lane >> 4;
    const int mycol = w * 16 + c;            // this lane's d-column, all layouts

    // ---- adjacency -> bf16 hi/lo planes ----
    {
        const float4* src = (const float4*)(subadj + (size_t)b * NM * NM);
        float4 v = src[tid];
        int e0 = tid * 4, i = e0 >> 5, j = e0 & 31;
        unsigned short h0 = bf_hi(v.x), h1 = bf_hi(v.y), h2 = bf_hi(v.z), h3 = bf_hi(v.w);
        unsigned short l0 = bf_hi(v.x - bf_f(h0)), l1 = bf_hi(v.y - bf_f(h1));
        unsigned short l2 = bf_hi(v.z - bf_f(h2)), l3 = bf_hi(v.w - bf_f(h3));
        int a = i * 40 + j;
        *(uint2*)&AH[a] = make_uint2((unsigned)h0 | ((unsigned)h1 << 16),
                                     (unsigned)h2 | ((unsigned)h3 << 16));
        *(uint2*)&AL[a] = make_uint2((unsigned)l0 | ((unsigned)l1 << 16),
                                     (unsigned)l2 | ((unsigned)l3 << 16));
    }

    // per-lane node embeddings (rows mt*16+4*gq+r at col mycol) + params
    float ev[8];
#pragma unroll
    for (int e = 0; e < 8; ++e) {
        int row = (e >> 2) * 16 + 4 * gq + (e & 3);
        int z = xg[b * NM + row];
        ev[e] = node_emb[z * HID + mycol];
    }
    float idv[3];
#pragma unroll
    for (int t = 0; t < 3; ++t) idv[t] = idemb[t * HID + mycol];
    const int nd0 = subgs[s * KSUB + 0];
    const int nd1 = subgs[s * KSUB + 1];
    const int nd2 = subgs[s * KSUB + 2];
    const int nn = num_node[b];
    float b1v[NLAYER], b2v[NLAYER], gv[NLAYER], bev[NLAYER];
#pragma unroll
    for (int l = 0; l < NLAYER; ++l) {
        b1v[l] = b1g[l * HID + mycol];
        b2v[l] = b2g[l * HID + mycol];
        gv[l]  = lngm[l * HID + mycol];
        bev[l] = lnbm[l * HID + mycol];
    }

    __syncthreads();

    // adjacency A-fragments, resident in regs: A[m=c+16mt][k=8*gq+j]
    bf16x8 afh[2], afl[2];
#pragma unroll
    for (int mt = 0; mt < 2; ++mt) {
        afh[mt] = *(const bf16x8*)&AH[(mt * 16 + c) * 40 + gq * 8];
        afl[mt] = *(const bf16x8*)&AL[(mt * 16 + c) * 40 + gq * 8];
    }

    float accv[8];
#pragma unroll
    for (int e = 0; e < 8; ++e) accv[e] = 0.f;

    for (int p = 0; p < PP; ++p) {
        // ---- init h (fp32, C-layout regs) ----
        float h[8];
#pragma unroll
        for (int e = 0; e < 8; ++e) {
            int row = (e >> 2) * 16 + 4 * gq + (e & 3);
            float hv = ev[e];
            if (row == nd0) hv *= idv[c_perm[0][p]];
            if (row == nd1) hv *= idv[c_perm[1][p]];
            if (row == nd2) hv *= idv[c_perm[2][p]];
            h[e] = hv;
        }

        for (int l = 0; l < NLAYER; ++l) {
            // (a) h -> X planes [row][d]
#pragma unroll
            for (int e = 0; e < 8; ++e) {
                int row = (e >> 2) * 16 + 4 * gq + (e & 3);
                int a = row * 72 + mycol;
                unsigned short hs = bf_hi(h[e]);
                XH[a] = hs;
                XL[a] = bf_hi(h[e] - bf_f(hs));
            }
            __syncthreads();

            // (c) GEMM-A: g = h @ W1[l]
            f32x4 gg[2] = {{0.f,0.f,0.f,0.f},{0.f,0.f,0.f,0.f}};
            {
                const unsigned short* w1h = wsu + W1H + (l * 64 + mycol) * 64;
                const unsigned short* w1l = wsu + W1L + (l * 64 + mycol) * 64;
#pragma unroll
                for (int ks = 0; ks < 2; ++ks) {
                    bf16x8 bh = *(const bf16x8*)(w1h + ks * 32 + gq * 8);
                    bf16x8 bl = *(const bf16x8*)(w1l + ks * 32 + gq * 8);
#pragma unroll
                    for (int mt = 0; mt < 2; ++mt) {
                        bf16x8 ah = *(const bf16x8*)&XH[(mt * 16 + c) * 72 + ks * 32 + gq * 8];
                        bf16x8 al = *(const bf16x8*)&XL[(mt * 16 + c) * 72 + ks * 32 + gq * 8];
                        gg[mt] = MFMA(ah, bh, gg[mt]);
                        gg[mt] = MFMA(ah, bl, gg[mt]);
                        gg[mt] = MFMA(al, bh, gg[mt]);
                    }
                }
            }
            // (d) g -> Y planes [d'][row] (C-layout writes are row-contiguous)
#pragma unroll
            for (int mt = 0; mt < 2; ++mt) {
                unsigned short yh4[4], yl4[4];
#pragma unroll
                for (int r = 0; r < 4; ++r) {
                    float v = gg[mt][r];
                    yh4[r] = bf_hi(v);
                    yl4[r] = bf_hi(v - bf_f(yh4[r]));
                }
                int a = mycol * 40 + mt * 16 + 4 * gq;
                *(uint2*)&YH[a] = make_uint2((unsigned)yh4[0] | ((unsigned)yh4[1] << 16),
                                             (unsigned)yh4[2] | ((unsigned)yh4[3] << 16));
                *(uint2*)&YL[a] = make_uint2((unsigned)yl4[0] | ((unsigned)yl4[1] << 16),
                                             (unsigned)yl4[2] | ((unsigned)yl4[3] << 16));
            }
            __syncthreads();

            // (f) GEMM-B: t = relu(A @ g + b1)
            f32x4 tt[2] = {{0.f,0.f,0.f,0.f},{0.f,0.f,0.f,0.f}};
            {
                bf16x8 bh = *(const bf16x8*)&YH[mycol * 40 + gq * 8];
                bf16x8 bl = *(const bf16x8*)&YL[mycol * 40 + gq * 8];
#pragma unroll
                for (int mt = 0; mt < 2; ++mt) {
                    tt[mt] = MFMA(afh[mt], bh, tt[mt]);
                    tt[mt] = MFMA(afh[mt], bl, tt[mt]);
                    tt[mt] = MFMA(afl[mt], bh, tt[mt]);
                }
            }
            // (g) t -> X planes [row][d'] (strided b16 transpose writes)
#pragma unroll
            for (int mt = 0; mt < 2; ++mt)
#pragma unroll
                for (int r = 0; r < 4; ++r) {
                    float tv = fmaxf(tt[mt][r] + b1v[l], 0.f);
                    int row = mt * 16 + 4 * gq + r;
                    int a = row * 72 + mycol;
                    unsigned short hs = bf_hi(tv);
                    XH[a] = hs;
                    XL[a] = bf_hi(tv - bf_f(hs));
                }
            __syncthreads();

            // (i) GEMM-C: u = t @ W2[l]
            f32x4 uu[2] = {{0.f,0.f,0.f,0.f},{0.f,0.f,0.f,0.f}};
            {
                const unsigned short* w2h = wsu + W2H + (l * 64 + mycol) * 64;
                const unsigned short* w2l = wsu + W2L + (l * 64 + mycol) * 64;
#pragma unroll
                for (int ks = 0; ks < 2; ++ks) {
                    bf16x8 bh = *(const bf16x8*)(w2h + ks * 32 + gq * 8);
                    bf16x8 bl = *(const bf16x8*)(w2l + ks * 32 + gq * 8);
#pragma unroll
                    for (int mt = 0; mt < 2; ++mt) {
                        bf16x8 ah = *(const bf16x8*)&XH[(mt * 16 + c) * 72 + ks * 32 + gq * 8];
                        bf16x8 al = *(const bf16x8*)&XL[(mt * 16 + c) * 72 + ks * 32 + gq * 8];
                        uu[mt] = MFMA(ah, bh, uu[mt]);
                        uu[mt] = MFMA(ah, bl, uu[mt]);
                        uu[mt] = MFMA(al, bh, uu[mt]);
                    }
                }
            }

            // (j) LayerNorm + relu + residual (fp32)
            float vv[8];
#pragma unroll
            for (int mt = 0; mt < 2; ++mt)
#pragma unroll
                for (int r = 0; r < 4; ++r)
                    vv[mt * 4 + r] = uu[mt][r] + b2v[l];
#pragma unroll
            for (int e = 0; e < 8; ++e) {
                float s1 = vv[e], s2 = vv[e] * vv[e];
#pragma unroll
                for (int off = 1; off < 16; off <<= 1) {
                    s1 += __shfl_xor(s1, off, 64);
                    s2 += __shfl_xor(s2, off, 64);
                }
                if (c == 0) {
                    int row = (e >> 2) * 16 + 4 * gq + (e & 3);
                    P1[row * 4 + w] = s1;
                    P2[row * 4 + w] = s2;
                }
            }
            __syncthreads();
#pragma unroll
            for (int e = 0; e < 8; ++e) {
                int row = (e >> 2) * 16 + 4 * gq + (e & 3);
                float4 q1 = *(const float4*)&P1[row * 4];
                float4 q2 = *(const float4*)&P2[row * 4];
                float s1 = q1.x + q1.y + q1.z + q1.w;
                float s2 = q2.x + q2.y + q2.z + q2.w;
                float mean = s1 * (1.0f / HID);
                float var  = s2 * (1.0f / HID) - mean * mean;
                float y = (vv[e] - mean) * rsqrtf(var + 1e-5f) * gv[l] + bev[l];
                h[e] += fmaxf(y, 0.f);
            }
        }
#pragma unroll
        for (int e = 0; e < 8; ++e) accv[e] += h[e];
    }

    // ---- perm mean + null mask -> X planes ----
#pragma unroll
    for (int e = 0; e < 8; ++e) {
        int row = (e >> 2) * 16 + 4 * gq + (e & 3);
        float hm = (row < nn) ? accv[e] * (1.0f / PP) : 0.f;
        int a = row * 72 + mycol;
        unsigned short hs = bf_hi(hm);
        XH[a] = hs;
        XL[a] = bf_hi(hm - bf_f(hs));
    }
    __syncthreads();

    // ---- GEMM-D: h1 = relu(hm @ set1_W + s1b); node-sum per column ----
    f32x4 hh[2] = {{0.f,0.f,0.f,0.f},{0.f,0.f,0.f,0.f}};
    {
        const unsigned short* s1h = wsu + S1H + mycol * 64;
        const unsigned short* s1l = wsu + S1L + mycol * 64;
#pragma unroll
        for (int ks = 0; ks < 2; ++ks) {
            bf16x8 bh = *(const bf16x8*)(s1h + ks * 32 + gq * 8);
            bf16x8 bl = *(const bf16x8*)(s1l + ks * 32 + gq * 8);
#pragma unroll
            for (int mt = 0; mt < 2; ++mt) {
                bf16x8 ah = *(const bf16x8*)&XH[(mt * 16 + c) * 72 + ks * 32 + gq * 8];
                bf16x8 al = *(const bf16x8*)&XL[(mt * 16 + c) * 72 + ks * 32 + gq * 8];
                hh[mt] = MFMA(ah, bh, hh[mt]);
                hh[mt] = MFMA(ah, bl, hh[mt]);
                hh[mt] = MFMA(al, bh, hh[mt]);
            }
        }
    }
    const float s1bv = s1bm[mycol];
    float colsum = 0.f;
#pragma unroll
    for (int mt = 0; mt < 2; ++mt)
#pragma unroll
        for (int r = 0; r < 4; ++r)
            colsum += fmaxf(hh[mt][r] + s1bv, 0.f);
    colsum += __shfl_xor(colsum, 16, 64);
    colsum += __shfl_xor(colsum, 32, 64);
    if (gq == 0) HS[mycol] = colsum;
    __syncthreads();

    // ---- h2 = relu(hsum @ set2_W + s2b)  (fp32 VALU, wave 0) ----
    if (tid < 64) {
        float acc = 0.f;
#pragma unroll
        for (int e = 0; e < HID; ++e)
            acc += HS[e] * s2wm[e * HID + tid];
        h2out[(size_t)s * HID + tid] = fmaxf(acc + s2bm[tid], 0.f);
    }
}

// segment_max over NS subgraphs per graph, then @ out_W + out_b
extern "C" __global__ void idmpnn_final(const float* __restrict__ h2,
                                        const float* __restrict__ outw,
                                        const float* __restrict__ outb,
                                        float* __restrict__ out)
{
    int b = blockIdx.x;
    int lane = threadIdx.x;
    float mx = -INFINITY;
    for (int t = 0; t < NS; ++t)
        mx = fmaxf(mx, h2[((size_t)b * NS + t) * HID + lane]);
    float v = mx * outw[lane];
#pragma unroll
    for (int off = 32; off > 0; off >>= 1) v += __shfl_xor(v, off, 64);
    if (lane == 0) out[b] = v + outb[0];
}

extern "C" void kernel_launch(void* const* d_in, const int* in_sizes, int n_in,
                              void* d_out, int out_size, void* d_ws, size_t ws_size,
                              hipStream_t stream)
{
    const int*   xg       = (const int*)d_in[0];
    const float* subadj   = (const float*)d_in[1];
    const int*   subgs    = (const int*)d_in[2];
    const int*   num_node = (const int*)d_in[3];
    const float* idemb    = (const float*)d_in[5];
    const float* node_emb = (const float*)d_in[6];
    const float* w1       = (const float*)d_in[7];
    const float* b1       = (const float*)d_in[8];
    const float* w2       = (const float*)d_in[9];
    const float* b2       = (const float*)d_in[10];
    const float* g        = (const float*)d_in[11];
    const float* be       = (const float*)d_in[12];
    const float* s1w      = (const float*)d_in[13];
    const float* s1b      = (const float*)d_in[14];
    const float* s2w      = (const float*)d_in[15];
    const float* s2b      = (const float*)d_in[16];
    const float* outw     = (const float*)d_in[17];
    const float* outb     = (const float*)d_in[18];

    unsigned short* wsu = (unsigned short*)d_ws;
    float* h2f = (float*)((char*)d_ws + H2_BYTE_OFF);

    idmpnn_prep<<<144, 256, 0, stream>>>(w1, w2, s1w, wsu);
    idmpnn_main<<<STOT, 256, 0, stream>>>(xg, subadj, subgs, num_node, idemb, node_emb,
                                          b1, b2, g, be, s1b, s2w, s2b, wsu, h2f);
    idmpnn_final<<<NBATCH, 64, 0, stream>>>(h2f, outw, outb, (float*)d_out);
}

// Round 3
// 315.256 us; speedup vs baseline: 4.6820x; 1.4111x over previous
//
#include <hip/hip_runtime.h>
#include <math.h>

// IDMPNN fused forward — wave-independent perm chains, transposed-GEMM MFMA.
// B=64, NM=32, NS=32, K=3, HID=64, NLAYER=4, P=6.
// Block = 192 thr (3 waves), one subgraph; wave w handles perms {2w, 2w+1}
// with a PRIVATE 9216B LDS buffer -> zero barriers inside the layer loop.
// GEMM chain oriented so producer-M == consumer-K: all LDS relayouts are
// contiguous uint4 writes of interleaved bf16 hi/lo chunks (trunc split,
// v_perm packing). Residual h + LN stay in fp32 regs (transposed C-layout).

#define NBATCH 64
#define NM 32
#define NS 32
#define KSUB 3
#define HID 64
#define NLAYER 4
#define PP 6
#define STOT (NBATCH * NS)

// d_ws ushort-offsets for weight planes ([dout][din] hi/lo, 64 per row)
#define W1H 0
#define W1L 16384
#define W2H 32768
#define W2L 49152
#define S1H 65536
#define S1L 69632
#define H2_BYTE_OFF 163840   // float[STOT*HID]

typedef short bf16x8 __attribute__((ext_vector_type(8)));
typedef float f32x4 __attribute__((ext_vector_type(4)));

#define MFMA(a, b, c) __builtin_amdgcn_mfma_f32_16x16x32_bf16(a, b, c, 0, 0, 0)

__constant__ int c_perm[KSUB][PP] = {
    {0, 0, 1, 1, 2, 2},
    {1, 2, 0, 2, 0, 1},
    {2, 1, 2, 0, 1, 0}
};

union FragU { struct { uint2 a, b; } u; bf16x8 f; };

// interleaved chunk layout: row of N d-elems = N/4 chunks of 16B:
//   bytes [0,8) = bf16-hi of d..d+3, [8,16) = bf16-lo (truncation split)
__device__ __forceinline__ bf16x8 frag_rd(const unsigned short* row, int dbase, int off) {
    FragU x;
    x.u.a = *(const uint2*)(row + dbase * 2 + off);
    x.u.b = *(const uint2*)(row + dbase * 2 + 8 + off);
    return x.f;
}

__device__ __forceinline__ void chunk_wr(unsigned short* row, int d0,
                                         float v0, float v1, float v2, float v3) {
    unsigned u0 = __float_as_uint(v0), u1 = __float_as_uint(v1);
    unsigned u2 = __float_as_uint(v2), u3 = __float_as_uint(v3);
    unsigned h0 = __builtin_amdgcn_perm(u1, u0, 0x07060302u);
    unsigned h1 = __builtin_amdgcn_perm(u3, u2, 0x07060302u);
    float r0 = v0 - __uint_as_float(u0 & 0xFFFF0000u);
    float r1 = v1 - __uint_as_float(u1 & 0xFFFF0000u);
    float r2 = v2 - __uint_as_float(u2 & 0xFFFF0000u);
    float r3 = v3 - __uint_as_float(u3 & 0xFFFF0000u);
    unsigned l0 = __builtin_amdgcn_perm(__float_as_uint(r1), __float_as_uint(r0), 0x07060302u);
    unsigned l1 = __builtin_amdgcn_perm(__float_as_uint(r3), __float_as_uint(r2), 0x07060302u);
    *(uint4*)(row + d0 * 2) = make_uint4(h0, h1, l0, l1);
}

__device__ __forceinline__ unsigned short bf_hi_rne(float x) {
    unsigned u = __float_as_uint(x);
    return (unsigned short)((u + 0x7FFFu + ((u >> 16) & 1u)) >> 16);
}
__device__ __forceinline__ float bf_f(unsigned short h) {
    return __uint_as_float(((unsigned)h) << 16);
}

// ---- prep: W1^T / W2^T / set1_W^T -> bf16 hi/lo planes [l][dout][din] ----
extern "C" __global__ void idmpnn_prep(const float* __restrict__ w1,
                                       const float* __restrict__ w2,
                                       const float* __restrict__ s1w,
                                       unsigned short* __restrict__ wsu)
{
    int idx = blockIdx.x * 256 + threadIdx.x;
    float v; int dh, dl;
    if (idx < 16384) {
        int l = idx >> 12, r = idx & 4095, dp = r >> 6, e = r & 63;
        v = w1[l * 4096 + e * 64 + dp];
        dh = W1H + idx; dl = W1L + idx;
    } else if (idx < 32768) {
        int k = idx - 16384;
        int l = k >> 12, r = k & 4095, dp = r >> 6, e = r & 63;
        v = w2[l * 4096 + e * 64 + dp];
        dh = W2H + k; dl = W2L + k;
    } else if (idx < 36864) {
        int k = idx - 32768, dp = k >> 6, e = k & 63;
        v = s1w[e * 64 + dp];
        dh = S1H + k; dl = S1L + k;
    } else return;
    unsigned short hi = bf_hi_rne(v);
    wsu[dh] = hi;
    wsu[dl] = bf_hi_rne(v - bf_f(hi));
}

extern "C" __global__ void __launch_bounds__(192, 2)
idmpnn_main(const int* __restrict__ xg, const float* __restrict__ subadj,
            const int* __restrict__ subgs, const int* __restrict__ num_node,
            const float* __restrict__ idemb, const float* __restrict__ node_emb,
            const float* __restrict__ b1g, const float* __restrict__ b2g,
            const float* __restrict__ lngm, const float* __restrict__ lnbm,
            const float* __restrict__ s1bm, const float* __restrict__ s2wm,
            const float* __restrict__ s2bm,
            const unsigned short* __restrict__ wsu, float* __restrict__ h2out)
{
    // per-wave private buffer: as HB [i][d] 32 rows x 272B, or GB [d'][i]
    // 64 rows x 144B, or f32 dump [32][64]. 4608 ushorts = 9216B each.
    __shared__ unsigned short WB[3 * 4608];
    __shared__ float evS[NM * 68];           // node_emb rows, f32
    __shared__ float idS[KSUB * 64];         // idemb rows 0..2
    __shared__ float prm[NLAYER * 4 * 64];   // b1,b2,g,be per layer
    __shared__ unsigned short HMB[NM * 136]; // perm-mean planes (interleaved)
    __shared__ float HS[HID];

    const int s = blockIdx.x, b = s >> 5;
    const int tid = threadIdx.x;
    const int w = tid / 64, lane = tid & 63;
    const int c = lane & 15, q = lane >> 4;

    // ---- block staging ----
    for (int idx = tid; idx < NM * HID; idx += 192) {
        int i = idx >> 6, d = idx & 63;
        evS[i * 68 + d] = node_emb[xg[b * NM + i] * HID + d];
    }
    for (int idx = tid; idx < NLAYER * 4 * 64; idx += 192) {
        int l = idx >> 8, r = idx & 255, wch = r >> 6, d = r & 63;
        const float* src = (wch == 0) ? b1g : (wch == 1) ? b2g : (wch == 2) ? lngm : lnbm;
        prm[idx] = src[l * HID + d];
    }
    if (tid < KSUB * 64) idS[tid] = idemb[tid];

    const int nd0 = subgs[s * KSUB + 0];
    const int nd1 = subgs[s * KSUB + 1];
    const int nd2 = subgs[s * KSUB + 2];
    const int nn = num_node[b];

    // ---- adjacency B-frags (adjT): lane holds adj[i=int*16+c][j=8q+jj], regs ----
    bf16x8 adjh[2], adjl[2];
#pragma unroll
    for (int in_ = 0; in_ < 2; ++in_) {
        const float* ap = subadj + (size_t)b * NM * NM + (in_ * 16 + c) * NM + 8 * q;
        float4 f0 = *(const float4*)ap;
        float4 f1 = *(const float4*)(ap + 4);
        unsigned a0 = __float_as_uint(f0.x), a1 = __float_as_uint(f0.y);
        unsigned a2 = __float_as_uint(f0.z), a3 = __float_as_uint(f0.w);
        unsigned a4 = __float_as_uint(f1.x), a5 = __float_as_uint(f1.y);
        unsigned a6 = __float_as_uint(f1.z), a7 = __float_as_uint(f1.w);
        FragU H, L;
        H.u.a.x = __builtin_amdgcn_perm(a1, a0, 0x07060302u);
        H.u.a.y = __builtin_amdgcn_perm(a3, a2, 0x07060302u);
        H.u.b.x = __builtin_amdgcn_perm(a5, a4, 0x07060302u);
        H.u.b.y = __builtin_amdgcn_perm(a7, a6, 0x07060302u);
        float r0 = f0.x - __uint_as_float(a0 & 0xFFFF0000u);
        float r1 = f0.y - __uint_as_float(a1 & 0xFFFF0000u);
        float r2 = f0.z - __uint_as_float(a2 & 0xFFFF0000u);
        float r3 = f0.w - __uint_as_float(a3 & 0xFFFF0000u);
        float r4 = f1.x - __uint_as_float(a4 & 0xFFFF0000u);
        float r5 = f1.y - __uint_as_float(a5 & 0xFFFF0000u);
        float r6 = f1.z - __uint_as_float(a6 & 0xFFFF0000u);
        float r7 = f1.w - __uint_as_float(a7 & 0xFFFF0000u);
        L.u.a.x = __builtin_amdgcn_perm(__float_as_uint(r1), __float_as_uint(r0), 0x07060302u);
        L.u.a.y = __builtin_amdgcn_perm(__float_as_uint(r3), __float_as_uint(r2), 0x07060302u);
        L.u.b.x = __builtin_amdgcn_perm(__float_as_uint(r5), __float_as_uint(r4), 0x07060302u);
        L.u.b.y = __builtin_amdgcn_perm(__float_as_uint(r7), __float_as_uint(r6), 0x07060302u);
        adjh[in_] = H.f;
        adjl[in_] = L.f;
    }

    __syncthreads();

    unsigned short* wb = WB + w * 4608;   // private buffer
    float accv[32];
#pragma unroll
    for (int e = 0; e < 32; ++e) accv[e] = 0.f;

    for (int pp = 0; pp < 2; ++pp) {
        const int p = w * 2 + pp;

        // ---- h init: transposed C-layout regs h[in_*16 + dm*4 + r]
        //      value at (i = in_*16+c, d = dm*16+4q+r) ----
        float h[32];
#pragma unroll
        for (int in_ = 0; in_ < 2; ++in_) {
            int i = in_ * 16 + c;
            int pid = (i == nd0) ? c_perm[0][p] : (i == nd1) ? c_perm[1][p]
                      : (i == nd2) ? c_perm[2][p] : -1;
#pragma unroll
            for (int dm = 0; dm < 4; ++dm) {
                float4 e4 = *(const float4*)&evS[i * 68 + dm * 16 + 4 * q];
                if (pid >= 0) {
                    float4 f4 = *(const float4*)&idS[pid * 64 + dm * 16 + 4 * q];
                    e4.x *= f4.x; e4.y *= f4.y; e4.z *= f4.z; e4.w *= f4.w;
                }
                h[in_ * 16 + dm * 4 + 0] = e4.x;
                h[in_ * 16 + dm * 4 + 1] = e4.y;
                h[in_ * 16 + dm * 4 + 2] = e4.z;
                h[in_ * 16 + dm * 4 + 3] = e4.w;
            }
        }

        for (int l = 0; l < NLAYER; ++l) {
            // (1) h -> HB [i][d]
#pragma unroll
            for (int in_ = 0; in_ < 2; ++in_)
#pragma unroll
                for (int dm = 0; dm < 4; ++dm)
                    chunk_wr(wb + (in_ * 16 + c) * 136, dm * 16 + 4 * q,
                             h[in_ * 16 + dm * 4 + 0], h[in_ * 16 + dm * 4 + 1],
                             h[in_ * 16 + dm * 4 + 2], h[in_ * 16 + dm * 4 + 3]);

            // (2) preload GEMM-A A-frags (before GB overwrites)
            bf16x8 hah[2][2], hal[2][2];
#pragma unroll
            for (int im = 0; im < 2; ++im)
#pragma unroll
                for (int ks = 0; ks < 2; ++ks) {
                    const unsigned short* row = wb + (im * 16 + c) * 136;
                    hah[im][ks] = frag_rd(row, ks * 32 + 8 * q, 0);
                    hal[im][ks] = frag_rd(row, ks * 32 + 8 * q, 4);
                }

            // (3) GEMM-A: g = h @ W1  (m=i, n=d', k=d)
            f32x4 gg[2][4];
#pragma unroll
            for (int im = 0; im < 2; ++im)
#pragma unroll
                for (int jn = 0; jn < 4; ++jn) gg[im][jn] = (f32x4){0.f, 0.f, 0.f, 0.f};
#pragma unroll
            for (int jn = 0; jn < 4; ++jn) {
                const unsigned short* w1h = wsu + W1H + (l * 64 + jn * 16 + c) * 64;
                const unsigned short* w1l = wsu + W1L + (l * 64 + jn * 16 + c) * 64;
#pragma unroll
                for (int ks = 0; ks < 2; ++ks) {
                    bf16x8 bh = *(const bf16x8*)(w1h + ks * 32 + 8 * q);
                    bf16x8 bl = *(const bf16x8*)(w1l + ks * 32 + 8 * q);
#pragma unroll
                    for (int im = 0; im < 2; ++im) {
                        gg[im][jn] = MFMA(hah[im][ks], bh, gg[im][jn]);
                        gg[im][jn] = MFMA(hah[im][ks], bl, gg[im][jn]);
                        gg[im][jn] = MFMA(hal[im][ks], bh, gg[im][jn]);
                    }
                }
            }

            // (4) g -> GB [d'][i]  (C m-runs contiguous)
#pragma unroll
            for (int jn = 0; jn < 4; ++jn)
#pragma unroll
                for (int im = 0; im < 2; ++im)
                    chunk_wr(wb + (jn * 16 + c) * 72, im * 16 + 4 * q,
                             gg[im][jn][0], gg[im][jn][1], gg[im][jn][2], gg[im][jn][3]);

            // (5) preload GEMM-B A-frags (g^T rows, k=j<32)
            bf16x8 gah[4], gal[4];
#pragma unroll
            for (int dm = 0; dm < 4; ++dm) {
                const unsigned short* row = wb + (dm * 16 + c) * 72;
                gah[dm] = frag_rd(row, 8 * q, 0);
                gal[dm] = frag_rd(row, 8 * q, 4);
            }

            // (6) GEMM-B: t^T = g^T @ adjT  (m=d', n=i, k=j)
            f32x4 tt[4][2];
#pragma unroll
            for (int dm = 0; dm < 4; ++dm)
#pragma unroll
                for (int in_ = 0; in_ < 2; ++in_) {
                    f32x4 z = (f32x4){0.f, 0.f, 0.f, 0.f};
                    z = MFMA(gah[dm], adjh[in_], z);
                    z = MFMA(gah[dm], adjl[in_], z);
                    z = MFMA(gal[dm], adjh[in_], z);
                    tt[dm][in_] = z;
                }

            // (7) t -> HB [i][d']  with relu(+b1)
            float4 b1v[4];
#pragma unroll
            for (int dm = 0; dm < 4; ++dm)
                b1v[dm] = *(const float4*)&prm[(l * 4 + 0) * 64 + dm * 16 + 4 * q];
#pragma unroll
            for (int in_ = 0; in_ < 2; ++in_)
#pragma unroll
                for (int dm = 0; dm < 4; ++dm)
                    chunk_wr(wb + (in_ * 16 + c) * 136, dm * 16 + 4 * q,
                             fmaxf(tt[dm][in_][0] + b1v[dm].x, 0.f),
                             fmaxf(tt[dm][in_][1] + b1v[dm].y, 0.f),
                             fmaxf(tt[dm][in_][2] + b1v[dm].z, 0.f),
                             fmaxf(tt[dm][in_][3] + b1v[dm].w, 0.f));

            // (8) preload GEMM-C B-frags (t rows, k=d')
            bf16x8 tbh[2][2], tbl[2][2];
#pragma unroll
            for (int in_ = 0; in_ < 2; ++in_)
#pragma unroll
                for (int ks = 0; ks < 2; ++ks) {
                    const unsigned short* row = wb + (in_ * 16 + c) * 136;
                    tbh[in_][ks] = frag_rd(row, ks * 32 + 8 * q, 0);
                    tbl[in_][ks] = frag_rd(row, ks * 32 + 8 * q, 4);
                }

            // (9) GEMM-C': u^T = W2^T @ t^T  (m=d, n=i, k=d')
            f32x4 uu[4][2];
#pragma unroll
            for (int dm = 0; dm < 4; ++dm)
#pragma unroll
                for (int in_ = 0; in_ < 2; ++in_) uu[dm][in_] = (f32x4){0.f, 0.f, 0.f, 0.f};
#pragma unroll
            for (int dm = 0; dm < 4; ++dm) {
                const unsigned short* w2h = wsu + W2H + (l * 64 + dm * 16 + c) * 64;
                const unsigned short* w2l = wsu + W2L + (l * 64 + dm * 16 + c) * 64;
#pragma unroll
                for (int ks = 0; ks < 2; ++ks) {
                    bf16x8 ah = *(const bf16x8*)(w2h + ks * 32 + 8 * q);
                    bf16x8 al = *(const bf16x8*)(w2l + ks * 32 + 8 * q);
#pragma unroll
                    for (int in_ = 0; in_ < 2; ++in_) {
                        uu[dm][in_] = MFMA(ah, tbh[in_][ks], uu[dm][in_]);
                        uu[dm][in_] = MFMA(ah, tbl[in_][ks], uu[dm][in_]);
                        uu[dm][in_] = MFMA(al, tbh[in_][ks], uu[dm][in_]);
                    }
                }
            }

            // (10) +b2, LayerNorm over d (lane-local 16 + 2 shfls), relu, residual
            float4 b2v[4], gv4[4], bev4[4];
#pragma unroll
            for (int dm = 0; dm < 4; ++dm) {
                b2v[dm]  = *(const float4*)&prm[(l * 4 + 1) * 64 + dm * 16 + 4 * q];
                gv4[dm]  = *(const float4*)&prm[(l * 4 + 2) * 64 + dm * 16 + 4 * q];
                bev4[dm] = *(const float4*)&prm[(l * 4 + 3) * 64 + dm * 16 + 4 * q];
            }
#pragma unroll
            for (int in_ = 0; in_ < 2; ++in_) {
                float v[16];
                float s1 = 0.f, s2 = 0.f;
#pragma unroll
                for (int dm = 0; dm < 4; ++dm) {
                    const float* bb = (const float*)&b2v[dm];
#pragma unroll
                    for (int r = 0; r < 4; ++r) {
                        float x = uu[dm][in_][r] + bb[r];
                        v[dm * 4 + r] = x;
                        s1 += x;
                        s2 += x * x;
                    }
                }
                s1 += __shfl_xor(s1, 16, 64); s1 += __shfl_xor(s1, 32, 64);
                s2 += __shfl_xor(s2, 16, 64); s2 += __shfl_xor(s2, 32, 64);
                float mean = s1 * (1.0f / HID);
                float var  = s2 * (1.0f / HID) - mean * mean;
                float rs   = rsqrtf(var + 1e-5f);
#pragma unroll
                for (int dm = 0; dm < 4; ++dm) {
                    const float* gp = (const float*)&gv4[dm];
                    const float* bp = (const float*)&bev4[dm];
#pragma unroll
                    for (int r = 0; r < 4; ++r) {
                        float y = (v[dm * 4 + r] - mean) * rs * gp[r] + bp[r];
                        h[in_ * 16 + dm * 4 + r] += fmaxf(y, 0.f);
                    }
                }
            }
        }
#pragma unroll
        for (int e = 0; e < 32; ++e) accv[e] += h[e];
    }

    // ---- dump 2-perm sums (f32 [i][d]) into private buffer ----
    {
        float* FB = (float*)wb;
#pragma unroll
        for (int in_ = 0; in_ < 2; ++in_)
#pragma unroll
            for (int dm = 0; dm < 4; ++dm) {
                float4 o;
                o.x = accv[in_ * 16 + dm * 4 + 0];
                o.y = accv[in_ * 16 + dm * 4 + 1];
                o.z = accv[in_ * 16 + dm * 4 + 2];
                o.w = accv[in_ * 16 + dm * 4 + 3];
                *(float4*)&FB[(in_ * 16 + c) * 64 + dm * 16 + 4 * q] = o;
            }
    }
    __syncthreads();

    // ---- combine perms: hm = mask * mean -> HMB planes ----
    {
        const float* F0 = (const float*)(WB + 0 * 4608);
        const float* F1 = (const float*)(WB + 1 * 4608);
        const float* F2 = (const float*)(WB + 2 * 4608);
        for (int idx = tid; idx < NM * HID; idx += 192) {
            int i = idx >> 6, d = idx & 63;
            float sv = F0[idx] + F1[idx] + F2[idx];
            float hm = (i < nn) ? sv * (1.0f / PP) : 0.f;
            unsigned u = __float_as_uint(hm);
            HMB[i * 136 + (d >> 2) * 8 + (d & 3)] = (unsigned short)(u >> 16);
            float rr = hm - __uint_as_float(u & 0xFFFF0000u);
            HMB[i * 136 + (d >> 2) * 8 + 4 + (d & 3)] = (unsigned short)(__float_as_uint(rr) >> 16);
        }
    }
    __syncthreads();

    // ---- tail (wave 0): GEMM-D set1 + colsum + set2 ----
    if (w == 0) {
        bf16x8 mah[2][2], mal[2][2];
#pragma unroll
        for (int im = 0; im < 2; ++im)
#pragma unroll
            for (int ks = 0; ks < 2; ++ks) {
                const unsigned short* row = HMB + (im * 16 + c) * 136;
                mah[im][ks] = frag_rd(row, ks * 32 + 8 * q, 0);
                mal[im][ks] = frag_rd(row, ks * 32 + 8 * q, 4);
            }
        f32x4 hh[2][4];
#pragma unroll
        for (int im = 0; im < 2; ++im)
#pragma unroll
            for (int jn = 0; jn < 4; ++jn) hh[im][jn] = (f32x4){0.f, 0.f, 0.f, 0.f};
#pragma unroll
        for (int jn = 0; jn < 4; ++jn) {
            const unsigned short* s1h = wsu + S1H + (jn * 16 + c) * 64;
            const unsigned short* s1l = wsu + S1L + (jn * 16 + c) * 64;
#pragma unroll
            for (int ks = 0; ks < 2; ++ks) {
                bf16x8 bh = *(const bf16x8*)(s1h + ks * 32 + 8 * q);
                bf16x8 bl = *(const bf16x8*)(s1l + ks * 32 + 8 * q);
#pragma unroll
                for (int im = 0; im < 2; ++im) {
                    hh[im][jn] = MFMA(mah[im][ks], bh, hh[im][jn]);
                    hh[im][jn] = MFMA(mah[im][ks], bl, hh[im][jn]);
                    hh[im][jn] = MFMA(mal[im][ks], bh, hh[im][jn]);
                }
            }
        }
        // colsum over all 32 rows (padded rows contribute relu(s1b) like ref)
#pragma unroll
        for (int jn = 0; jn < 4; ++jn) {
            float sb = s1bm[jn * 16 + c];
            float cs = 0.f;
#pragma unroll
            for (int im = 0; im < 2; ++im)
#pragma unroll
                for (int r = 0; r < 4; ++r)
                    cs += fmaxf(hh[im][jn][r] + sb, 0.f);
            cs += __shfl_xor(cs, 16, 64);
            cs += __shfl_xor(cs, 32, 64);
            if (q == 0) HS[jn * 16 + c] = cs;
        }
        // h2 = relu(HS @ set2_W + s2b)
        float acc = 0.f;
#pragma unroll
        for (int e = 0; e < HID; ++e)
            acc += HS[e] * s2wm[e * HID + lane];
        h2out[(size_t)s * HID + lane] = fmaxf(acc + s2bm[lane], 0.f);
    }
}

// segment_max over NS subgraphs per graph, then @ out_W + out_b
extern "C" __global__ void idmpnn_final(const float* __restrict__ h2,
                                        const float* __restrict__ outw,
                                        const float* __restrict__ outb,
                                        float* __restrict__ out)
{
    int b = blockIdx.x;
    int lane = threadIdx.x;
    float mx = -INFINITY;
    for (int t = 0; t < NS; ++t)
        mx = fmaxf(mx, h2[((size_t)b * NS + t) * HID + lane]);
    float v = mx * outw[lane];
#pragma unroll
    for (int off = 32; off > 0; off >>= 1) v += __shfl_xor(v, off, 64);
    if (lane == 0) out[b] = v + outb[0];
}

extern "C" void kernel_launch(void* const* d_in, const int* in_sizes, int n_in,
                              void* d_out, int out_size, void* d_ws, size_t ws_size,
                              hipStream_t stream)
{
    const int*   xg       = (const int*)d_in[0];
    const float* subadj   = (const float*)d_in[1];
    const int*   subgs    = (const int*)d_in[2];
    const int*   num_node = (const int*)d_in[3];
    const float* idemb    = (const float*)d_in[5];
    const float* node_emb = (const float*)d_in[6];
    const float* w1       = (const float*)d_in[7];
    const float* b1       = (const float*)d_in[8];
    const float* w2       = (const float*)d_in[9];
    const float* b2       = (const float*)d_in[10];
    const float* g        = (const float*)d_in[11];
    const float* be       = (const float*)d_in[12];
    const float* s1w      = (const float*)d_in[13];
    const float* s1b      = (const float*)d_in[14];
    const float* s2w      = (const float*)d_in[15];
    const float* s2b      = (const float*)d_in[16];
    const float* outw     = (const float*)d_in[17];
    const float* outb     = (const float*)d_in[18];

    unsigned short* wsu = (unsigned short*)d_ws;
    float* h2f = (float*)((char*)d_ws + H2_BYTE_OFF);

    idmpnn_prep<<<144, 256, 0, stream>>>(w1, w2, s1w, wsu);
    idmpnn_main<<<STOT, 192, 0, stream>>>(xg, subadj, subgs, num_node, idemb, node_emb,
                                          b1, b2, g, be, s1b, s2w, s2b, wsu, h2f);
    idmpnn_final<<<NBATCH, 64, 0, stream>>>(h2f, outw, outb, (float*)d_out);
}